// Round 1
// baseline (1554.238 us; speedup 1.0000x reference)
//
#include <hip/hip_runtime.h>
#include <math.h>

#define BN 4
#define CIN 128
#define COUT 64
#define WSDIM 512
#define HI 128
#define WI 128
#define HO 256
#define WO 256
#define EPSC 1e-8f

static __device__ __forceinline__ float lrelu(float v) { return v > 0.f ? v : 0.2f * v; }

// ---------------- styles + demod factors ----------------
__global__ __launch_bounds__(128) void k_styles(
    const float* __restrict__ w, const float* __restrict__ c1w, const float* __restrict__ c2w,
    const float* __restrict__ a1w, const float* __restrict__ a1b,
    const float* __restrict__ a2w, const float* __restrict__ a2b,
    float* __restrict__ s1, float* __restrict__ s2,
    float* __restrict__ d1g, float* __restrict__ d2g)
{
  const int b = blockIdx.x;
  const int t = threadIdx.x;
  const float he_a = 0.044194173824159216f;           // 1/sqrt(512)
  const float GAIN = 1.3867504905630728f;             // sqrt(2/1.04)
  const float he1 = GAIN / 33.941125496954285f;       // GAIN/sqrt(128*9)
  const float he2 = GAIN / 24.0f;                     // GAIN/sqrt(64*9)
  __shared__ float sh1[CIN];
  __shared__ float sh2[COUT];
  const float* wv = w + b * WSDIM;

  { // s1[t], t in 0..127
    float acc = 0.f;
    const float* ap = a1w + t * WSDIM;
    for (int k = 0; k < WSDIM; ++k) acc += ap[k] * wv[k];
    float v = acc * he_a + a1b[t];
    sh1[t] = v;
    s1[b * CIN + t] = v;
  }
  if (t < COUT) {
    float acc = 0.f;
    const float* ap = a2w + t * WSDIM;
    for (int k = 0; k < WSDIM; ++k) acc += ap[k] * wv[k];
    float v = acc * he_a + a2b[t];
    sh2[t] = v;
    s2[b * COUT + t] = v;
  }
  __syncthreads();
  if (t < COUT) {
    float acc = 0.f;
    for (int c = 0; c < CIN; ++c) {
      const float* wp = c1w + (c * COUT + t) * 9;
      float ws_ = 0.f;
      #pragma unroll
      for (int k = 0; k < 9; ++k) ws_ += wp[k] * wp[k];
      acc += sh1[c] * sh1[c] * ws_;
    }
    d1g[b * COUT + t] = rsqrtf(acc * he1 * he1 + EPSC) * GAIN;

    float acc2 = 0.f;
    for (int c = 0; c < COUT; ++c) {
      const float* wp = c2w + (c * COUT + t) * 9;
      float ws_ = 0.f;
      #pragma unroll
      for (int k = 0; k < 9; ++k) ws_ += wp[k] * wp[k];
      acc2 += sh2[c] * sh2[c] * ws_;
    }
    d2g[b * COUT + t] = rsqrtf(acc2 * he2 * he2 + EPSC) * GAIN;
  }
}

// ---------------- conv1: fused upsample + modulated conv + noise + lrelu ----------------
__global__ __launch_bounds__(256) void k_conv1(
    const float* __restrict__ x, const float* __restrict__ c1w,
    const float* __restrict__ noise1, const float* __restrict__ bias1, const float* __restrict__ baff1,
    const float* __restrict__ s1, const float* __restrict__ d1g,
    float* __restrict__ h1)
{
  const int b = blockIdx.z;
  const int oy0 = blockIdx.y * 16, ox0 = blockIdx.x * 16;
  const int tid = threadIdx.x;
  const int tx = tid & 15, ty = tid >> 4;
  const int oy = oy0 + ty, ox = ox0 + tx;

  __shared__ float tile[18][20];
  float acc[COUT];
  #pragma unroll
  for (int o = 0; o < COUT; ++o) acc[o] = 0.f;

  const float he1 = 1.3867504905630728f / 33.941125496954285f;
  const float S = 127.0f / 255.0f;

  for (int c = 0; c < CIN; ++c) {
    const float sc = s1[b * CIN + c] * he1;
    const float* xc = x + ((size_t)(b * CIN + c)) * HI * WI;
    for (int idx = tid; idx < 18 * 18; idx += 256) {
      int r = idx / 18, col = idx - r * 18;
      int yy = oy0 - 1 + r, xx = ox0 - 1 + col;
      float v = 0.f;
      if (yy >= 0 && yy < HO && xx >= 0 && xx < WO) {
        float fy = yy * S; int y0 = (int)fy; float wy = fy - (float)y0; int y1 = min(y0 + 1, HI - 1);
        float fx = xx * S; int x0 = (int)fx; float wx = fx - (float)x0; int x1 = min(x0 + 1, WI - 1);
        float a  = xc[y0 * WI + x0], bq = xc[y0 * WI + x1];
        float cq = xc[y1 * WI + x0], dq = xc[y1 * WI + x1];
        float t0 = a  * (1.f - wy) + cq * wy;
        float t1 = bq * (1.f - wy) + dq * wy;
        v = (t0 * (1.f - wx) + t1 * wx) * sc;
      }
      tile[r][col] = v;
    }
    __syncthreads();
    float v0 = tile[ty + 0][tx + 0], v1 = tile[ty + 0][tx + 1], v2 = tile[ty + 0][tx + 2];
    float v3 = tile[ty + 1][tx + 0], v4 = tile[ty + 1][tx + 1], v5 = tile[ty + 1][tx + 2];
    float v6 = tile[ty + 2][tx + 0], v7 = tile[ty + 2][tx + 1], v8 = tile[ty + 2][tx + 2];
    const float* wc = c1w + (size_t)c * COUT * 9;
    #pragma unroll
    for (int o = 0; o < COUT; ++o) {
      const float* wp = wc + o * 9;   // flipped kernel: element (dy,dx) -> wp[8-k]
      acc[o] += v0 * wp[8] + v1 * wp[7] + v2 * wp[6]
              + v3 * wp[5] + v4 * wp[4] + v5 * wp[3]
              + v6 * wp[2] + v7 * wp[1] + v8 * wp[0];
    }
    __syncthreads();
  }

  const float n1 = noise1[(size_t)b * HO * WO + oy * WO + ox];
  #pragma unroll
  for (int o = 0; o < COUT; ++o) {
    float v = acc[o] * d1g[b * COUT + o] + n1 * baff1[o] + bias1[o];
    h1[(((size_t)(b * COUT + o)) * HO + oy) * WO + ox] = lrelu(v);
  }
}

// ---------------- conv2 + noise + lrelu + rgb ----------------
__global__ __launch_bounds__(256) void k_conv2(
    const float* __restrict__ h1, const float* __restrict__ c2w,
    const float* __restrict__ noise2, const float* __restrict__ bias2, const float* __restrict__ baff2,
    const float* __restrict__ s2, const float* __restrict__ d2g,
    const float* __restrict__ rgbw, const float* __restrict__ rgbb,
    float* __restrict__ hout, float* __restrict__ rgbout)
{
  const int b = blockIdx.z;
  const int oy0 = blockIdx.y * 16, ox0 = blockIdx.x * 16;
  const int tid = threadIdx.x;
  const int tx = tid & 15, ty = tid >> 4;
  const int oy = oy0 + ty, ox = ox0 + tx;

  __shared__ float tile[18][20];
  float acc[COUT];
  #pragma unroll
  for (int o = 0; o < COUT; ++o) acc[o] = 0.f;

  const float he2 = 1.3867504905630728f / 24.0f;

  for (int c = 0; c < COUT; ++c) {
    const float sc = s2[b * COUT + c] * he2;
    const float* hc = h1 + ((size_t)(b * COUT + c)) * HO * WO;
    for (int idx = tid; idx < 18 * 18; idx += 256) {
      int r = idx / 18, col = idx - r * 18;
      int yy = oy0 - 1 + r, xx = ox0 - 1 + col;
      float v = 0.f;
      if (yy >= 0 && yy < HO && xx >= 0 && xx < WO) v = hc[yy * WO + xx] * sc;
      tile[r][col] = v;
    }
    __syncthreads();
    float v0 = tile[ty + 0][tx + 0], v1 = tile[ty + 0][tx + 1], v2 = tile[ty + 0][tx + 2];
    float v3 = tile[ty + 1][tx + 0], v4 = tile[ty + 1][tx + 1], v5 = tile[ty + 1][tx + 2];
    float v6 = tile[ty + 2][tx + 0], v7 = tile[ty + 2][tx + 1], v8 = tile[ty + 2][tx + 2];
    const float* wc = c2w + (size_t)c * COUT * 9;
    #pragma unroll
    for (int o = 0; o < COUT; ++o) {
      const float* wp = wc + o * 9;
      acc[o] += v0 * wp[8] + v1 * wp[7] + v2 * wp[6]
              + v3 * wp[5] + v4 * wp[4] + v5 * wp[3]
              + v6 * wp[2] + v7 * wp[1] + v8 * wp[0];
    }
    __syncthreads();
  }

  const float n2 = noise2[(size_t)b * HO * WO + oy * WO + ox];
  const float he_rgb = 0.00375f;   // 0.03/sqrt(64)
  float r0 = 0.f, r1 = 0.f, r2 = 0.f;
  #pragma unroll
  for (int o = 0; o < COUT; ++o) {
    float v = lrelu(acc[o] * d2g[b * COUT + o] + n2 * baff2[o] + bias2[o]);
    hout[(((size_t)(b * COUT + o)) * HO + oy) * WO + ox] = v;
    r0 += rgbw[0 * COUT + o] * v;
    r1 += rgbw[1 * COUT + o] * v;
    r2 += rgbw[2 * COUT + o] * v;
  }
  rgbout[(((size_t)(b * 3 + 0)) * HO + oy) * WO + ox] = r0 * he_rgb + rgbb[0];
  rgbout[(((size_t)(b * 3 + 1)) * HO + oy) * WO + ox] = r1 * he_rgb + rgbb[1];
  rgbout[(((size_t)(b * 3 + 2)) * HO + oy) * WO + ox] = r2 * he_rgb + rgbb[2];
}

extern "C" void kernel_launch(void* const* d_in, const int* in_sizes, int n_in,
                              void* d_out, int out_size, void* d_ws, size_t ws_size,
                              hipStream_t stream) {
  const float* x      = (const float*)d_in[0];
  const float* w      = (const float*)d_in[1];
  const float* c1w    = (const float*)d_in[2];
  const float* c2w    = (const float*)d_in[3];
  const float* bias1  = (const float*)d_in[4];
  const float* bias2  = (const float*)d_in[5];
  const float* a1w    = (const float*)d_in[6];
  const float* a1b    = (const float*)d_in[7];
  const float* a2w    = (const float*)d_in[8];
  const float* a2b    = (const float*)d_in[9];
  const float* baff1  = (const float*)d_in[10];
  const float* baff2  = (const float*)d_in[11];
  const float* rgbw   = (const float*)d_in[12];
  const float* rgbb   = (const float*)d_in[13];
  const float* noise1 = (const float*)d_in[14];
  const float* noise2 = (const float*)d_in[15];

  float* h1  = (float*)d_ws;                                   // B*64*256*256 floats = 64 MiB
  float* sty = (float*)((char*)d_ws + (size_t)BN * COUT * HO * WO * sizeof(float));
  float* s1  = sty;
  float* s2  = s1 + BN * CIN;
  float* d1g = s2 + BN * COUT;
  float* d2g = d1g + BN * COUT;

  float* hout   = (float*)d_out;
  float* rgbout = hout + (size_t)BN * COUT * HO * WO;

  k_styles<<<BN, 128, 0, stream>>>(w, c1w, c2w, a1w, a1b, a2w, a2b, s1, s2, d1g, d2g);
  dim3 grid(WO / 16, HO / 16, BN);
  k_conv1<<<grid, 256, 0, stream>>>(x, c1w, noise1, bias1, baff1, s1, d1g, h1);
  k_conv2<<<grid, 256, 0, stream>>>(h1, c2w, noise2, bias2, baff2, s2, d2g, rgbw, rgbb, hout, rgbout);
}

// Round 2
// 184.719 us; speedup vs baseline: 8.4141x; 8.4141x over previous
//
#include <hip/hip_runtime.h>
#include <hip/hip_bf16.h>
#include <math.h>

#define BN 4
#define CIN 128
#define COUT 64
#define WSDIM 512
#define HI 128
#define WI 128
#define HO 256
#define WO 256
#define EPSC 1e-8f
#define GAINC 1.3867504905630728f
#define HE1 (GAINC/33.941125496954285f)
#define HE2 (GAINC/24.0f)
#define SUP (127.0f/255.0f)

typedef __attribute__((ext_vector_type(8))) short s16x8;
typedef __attribute__((ext_vector_type(4))) float f32x4_t;
typedef __attribute__((ext_vector_type(4))) unsigned int u32x4;

static __device__ __forceinline__ float lrelu(float v){ return v > 0.f ? v : 0.2f*v; }
static __device__ __forceinline__ unsigned short bfbits(float v){
  __hip_bfloat16 h = __float2bfloat16(v);
  return *reinterpret_cast<unsigned short*>(&h);
}
static __device__ __forceinline__ unsigned int packbf(float a, float b){
  return (unsigned int)bfbits(a) | ((unsigned int)bfbits(b) << 16);
}

// ---------------- styles + demod factors (unchanged, proven) ----------------
__global__ __launch_bounds__(128) void k_styles(
    const float* __restrict__ w, const float* __restrict__ c1w, const float* __restrict__ c2w,
    const float* __restrict__ a1w, const float* __restrict__ a1b,
    const float* __restrict__ a2w, const float* __restrict__ a2b,
    float* __restrict__ s1, float* __restrict__ s2,
    float* __restrict__ d1g, float* __restrict__ d2g)
{
  const int b = blockIdx.x;
  const int t = threadIdx.x;
  const float he_a = 0.044194173824159216f;
  __shared__ float sh1[CIN];
  __shared__ float sh2[COUT];
  const float* wv = w + b * WSDIM;

  {
    float acc = 0.f;
    const float* ap = a1w + t * WSDIM;
    for (int k = 0; k < WSDIM; ++k) acc += ap[k] * wv[k];
    float v = acc * he_a + a1b[t];
    sh1[t] = v;
    s1[b * CIN + t] = v;
  }
  if (t < COUT) {
    float acc = 0.f;
    const float* ap = a2w + t * WSDIM;
    for (int k = 0; k < WSDIM; ++k) acc += ap[k] * wv[k];
    float v = acc * he_a + a2b[t];
    sh2[t] = v;
    s2[b * COUT + t] = v;
  }
  __syncthreads();
  if (t < COUT) {
    float acc = 0.f;
    for (int c = 0; c < CIN; ++c) {
      const float* wp = c1w + (c * COUT + t) * 9;
      float ws_ = 0.f;
      #pragma unroll
      for (int k = 0; k < 9; ++k) ws_ += wp[k] * wp[k];
      acc += sh1[c] * sh1[c] * ws_;
    }
    d1g[b * COUT + t] = rsqrtf(acc * HE1 * HE1 + EPSC) * GAINC;

    float acc2 = 0.f;
    for (int c = 0; c < COUT; ++c) {
      const float* wp = c2w + (c * COUT + t) * 9;
      float ws_ = 0.f;
      #pragma unroll
      for (int k = 0; k < 9; ++k) ws_ += wp[k] * wp[k];
      acc2 += sh2[c] * sh2[c] * ws_;
    }
    d2g[b * COUT + t] = rsqrtf(acc2 * HE2 * HE2 + EPSC) * GAINC;
  }
}

// ---------------- weight prep: pre-swizzled bf16 B-fragments ----------------
// B-frag layout for mfma_f32_16x16x32_bf16: lane l holds k=(l>>4)*8+j, n=l&15.
// Group g = ((cc*9 + k)*4 + ot); element (l,j): c = cc*32+(l>>4)*8+j, o = ot*16+(l&15).
// Kernel flip baked in: tap k uses w[...][8-k]. he folded in.
__global__ __launch_bounds__(256) void k_wprep(
    const float* __restrict__ c1w, const float* __restrict__ c2w,
    unsigned short* __restrict__ B1, unsigned short* __restrict__ B2)
{
  const int g = blockIdx.x, t = threadIdx.x;
  if (g < 144) {
    int cc = g / 36, r = g - cc * 36, k = r >> 2, ot = r & 3;
    for (int e = t; e < 512; e += 256) {
      int l = e >> 3, j = e & 7;
      int c = cc * 32 + (l >> 4) * 8 + j, o = ot * 16 + (l & 15);
      B1[g * 512 + e] = bfbits(c1w[(c * COUT + o) * 9 + (8 - k)] * HE1);
    }
  } else {
    int g2 = g - 144;
    int cc = g2 / 36, r = g2 - cc * 36, k = r >> 2, ot = r & 3;
    for (int e = t; e < 512; e += 256) {
      int l = e >> 3, j = e & 7;
      int c = cc * 32 + (l >> 4) * 8 + j, o = ot * 16 + (l & 15);
      B2[g2 * 512 + e] = bfbits(c2w[(c * COUT + o) * 9 + (8 - k)] * HE2);
    }
  }
}

// ---------------- conv1: upsample+modulate staged to LDS, MFMA, fused epilogue ----------------
// LDS tile: rows rr = ys*18+xs (18x18 spatial halo), each row = 32 bf16 channels,
// row stride 80B (20 dwords) -> 16B aligned, 2-way bank aliasing (free).
__global__ __launch_bounds__(256) void k_conv1(
    const float* __restrict__ x, const unsigned short* __restrict__ B1pre,
    const float* __restrict__ noise1, const float* __restrict__ bias1, const float* __restrict__ baff1,
    const float* __restrict__ s1, const float* __restrict__ d1g, const float* __restrict__ s2,
    unsigned short* __restrict__ h1)
{
  const int b = blockIdx.z;
  const int oy0 = blockIdx.y * 16, ox0 = blockIdx.x * 16;
  const int tid = threadIdx.x;
  const int lane = tid & 63, wv = tid >> 6;
  const int lx = lane & 15, lg = lane >> 4;

  __shared__ unsigned int ldsA[324 * 20];

  f32x4_t acc[4][4];
  #pragma unroll
  for (int i = 0; i < 4; ++i)
    #pragma unroll
    for (int j = 0; j < 4; ++j) acc[i][j] = (f32x4_t){0.f, 0.f, 0.f, 0.f};

  const s16x8* Bb = (const s16x8*)B1pre;

  for (int cc = 0; cc < 4; ++cc) {
    // ---- stage: bilinear upsample * s1 -> bf16 LDS tile ----
    for (int rr = tid; rr < 324; rr += 256) {
      int ys = rr / 18, xs = rr - ys * 18;
      int yy = oy0 - 1 + ys, xx = ox0 - 1 + xs;
      unsigned int* dst = ldsA + rr * 20;
      bool inr = (yy >= 0) && (yy < HO) && (xx >= 0) && (xx < WO);
      float wyl = 0.f, wxl = 0.f;
      int p00 = 0, p01 = 0, p10 = 0, p11 = 0;
      if (inr) {
        float fy = yy * SUP; int y0 = (int)fy; wyl = fy - (float)y0; int y1 = min(y0 + 1, HI - 1);
        float fx = xx * SUP; int x0 = (int)fx; wxl = fx - (float)x0; int x1 = min(x0 + 1, WI - 1);
        p00 = y0 * WI + x0; p01 = y0 * WI + x1; p10 = y1 * WI + x0; p11 = y1 * WI + x1;
      }
      const float* xb = x + (((size_t)b * CIN + cc * 32) << 14);
      const float* s1p = s1 + b * CIN + cc * 32;
      #pragma unroll
      for (int q = 0; q < 4; ++q) {
        unsigned int w0 = 0, w1 = 0, w2 = 0, w3 = 0;
        if (inr) {
          float vv[8];
          #pragma unroll
          for (int e = 0; e < 8; ++e) {
            const float* xc = xb + ((size_t)(q * 8 + e) << 14);
            float t0 = xc[p00] + (xc[p10] - xc[p00]) * wyl;
            float t1 = xc[p01] + (xc[p11] - xc[p01]) * wyl;
            vv[e] = (t0 + (t1 - t0) * wxl) * s1p[q * 8 + e];
          }
          w0 = packbf(vv[0], vv[1]); w1 = packbf(vv[2], vv[3]);
          w2 = packbf(vv[4], vv[5]); w3 = packbf(vv[6], vv[7]);
        }
        u32x4 wq = {w0, w1, w2, w3};
        *((u32x4*)dst + q) = wq;
      }
    }
    __syncthreads();
    // ---- compute: 9 taps x 4 y-rows x 4 out-tiles ----
    #pragma unroll
    for (int k = 0; k < 9; ++k) {
      const int dy = k / 3, dx = k - 3 * (k / 3);
      s16x8 b0 = Bb[((cc * 9 + k) * 4 + 0) * 64 + lane];
      s16x8 b1 = Bb[((cc * 9 + k) * 4 + 1) * 64 + lane];
      s16x8 b2 = Bb[((cc * 9 + k) * 4 + 2) * 64 + lane];
      s16x8 b3 = Bb[((cc * 9 + k) * 4 + 3) * 64 + lane];
      #pragma unroll
      for (int yi = 0; yi < 4; ++yi) {
        int row = (wv * 4 + yi + dy) * 18 + (lx + dx);
        s16x8 a = *(const s16x8*)((const char*)ldsA + (size_t)row * 80 + lg * 16);
        acc[yi][0] = __builtin_amdgcn_mfma_f32_16x16x32_bf16(a, b0, acc[yi][0], 0, 0, 0);
        acc[yi][1] = __builtin_amdgcn_mfma_f32_16x16x32_bf16(a, b1, acc[yi][1], 0, 0, 0);
        acc[yi][2] = __builtin_amdgcn_mfma_f32_16x16x32_bf16(a, b2, acc[yi][2], 0, 0, 0);
        acc[yi][3] = __builtin_amdgcn_mfma_f32_16x16x32_bf16(a, b3, acc[yi][3], 0, 0, 0);
      }
    }
    __syncthreads();
  }
  // ---- epilogue: demod + noise + bias + lrelu, fold s2, store bf16 channel-last ----
  #pragma unroll
  for (int yi = 0; yi < 4; ++yi) {
    int y = oy0 + wv * 4 + yi;
    f32x4_t nv = *(const f32x4_t*)(noise1 + (size_t)b * HO * WO + (size_t)y * WO + ox0 + lg * 4);
    #pragma unroll
    for (int ot = 0; ot < 4; ++ot) {
      int o = ot * 16 + lx;
      float d = d1g[b * COUT + o], ba = baff1[o], bi = bias1[o], sv = s2[b * COUT + o];
      #pragma unroll
      for (int jj = 0; jj < 4; ++jj) {
        float v = acc[yi][ot][jj] * d + nv[jj] * ba + bi;
        v = lrelu(v) * sv;
        int xg = ox0 + lg * 4 + jj;
        h1[(((size_t)b * HO + y) * WO + xg) * COUT + o] = bfbits(v);
      }
    }
  }
}

// ---------------- conv2: h1 (bf16, s2 folded) -> MFMA -> h out (fp32) ----------------
__global__ __launch_bounds__(256) void k_conv2(
    const unsigned short* __restrict__ h1, const unsigned short* __restrict__ B2pre,
    const float* __restrict__ noise2, const float* __restrict__ bias2, const float* __restrict__ baff2,
    const float* __restrict__ d2g, float* __restrict__ hout)
{
  const int b = blockIdx.z;
  const int oy0 = blockIdx.y * 16, ox0 = blockIdx.x * 16;
  const int tid = threadIdx.x;
  const int lane = tid & 63, wv = tid >> 6;
  const int lx = lane & 15, lg = lane >> 4;

  __shared__ unsigned int ldsA[324 * 20];

  f32x4_t acc[4][4];
  #pragma unroll
  for (int i = 0; i < 4; ++i)
    #pragma unroll
    for (int j = 0; j < 4; ++j) acc[i][j] = (f32x4_t){0.f, 0.f, 0.f, 0.f};

  const s16x8* Bb = (const s16x8*)B2pre;

  for (int cc = 0; cc < 2; ++cc) {
    for (int rr = tid; rr < 324; rr += 256) {
      int ys = rr / 18, xs = rr - ys * 18;
      int yy = oy0 - 1 + ys, xx = ox0 - 1 + xs;
      u32x4 v0 = {0,0,0,0}, v1 = {0,0,0,0}, v2 = {0,0,0,0}, v3 = {0,0,0,0};
      if ((yy >= 0) && (yy < HO) && (xx >= 0) && (xx < WO)) {
        const u32x4* src = (const u32x4*)(h1 + ((((size_t)b * HO + yy) * WO + xx) * COUT + cc * 32));
        v0 = src[0]; v1 = src[1]; v2 = src[2]; v3 = src[3];
      }
      unsigned int* dst = ldsA + rr * 20;
      ((u32x4*)dst)[0] = v0; ((u32x4*)dst)[1] = v1;
      ((u32x4*)dst)[2] = v2; ((u32x4*)dst)[3] = v3;
    }
    __syncthreads();
    #pragma unroll
    for (int k = 0; k < 9; ++k) {
      const int dy = k / 3, dx = k - 3 * (k / 3);
      s16x8 b0 = Bb[((cc * 9 + k) * 4 + 0) * 64 + lane];
      s16x8 b1 = Bb[((cc * 9 + k) * 4 + 1) * 64 + lane];
      s16x8 b2 = Bb[((cc * 9 + k) * 4 + 2) * 64 + lane];
      s16x8 b3 = Bb[((cc * 9 + k) * 4 + 3) * 64 + lane];
      #pragma unroll
      for (int yi = 0; yi < 4; ++yi) {
        int row = (wv * 4 + yi + dy) * 18 + (lx + dx);
        s16x8 a = *(const s16x8*)((const char*)ldsA + (size_t)row * 80 + lg * 16);
        acc[yi][0] = __builtin_amdgcn_mfma_f32_16x16x32_bf16(a, b0, acc[yi][0], 0, 0, 0);
        acc[yi][1] = __builtin_amdgcn_mfma_f32_16x16x32_bf16(a, b1, acc[yi][1], 0, 0, 0);
        acc[yi][2] = __builtin_amdgcn_mfma_f32_16x16x32_bf16(a, b2, acc[yi][2], 0, 0, 0);
        acc[yi][3] = __builtin_amdgcn_mfma_f32_16x16x32_bf16(a, b3, acc[yi][3], 0, 0, 0);
      }
    }
    __syncthreads();
  }
  #pragma unroll
  for (int yi = 0; yi < 4; ++yi) {
    int y = oy0 + wv * 4 + yi;
    f32x4_t nv = *(const f32x4_t*)(noise2 + (size_t)b * HO * WO + (size_t)y * WO + ox0 + lg * 4);
    #pragma unroll
    for (int ot = 0; ot < 4; ++ot) {
      int o = ot * 16 + lx;
      float d = d2g[b * COUT + o], ba = baff2[o], bi = bias2[o];
      f32x4_t hv;
      #pragma unroll
      for (int jj = 0; jj < 4; ++jj) {
        float v = acc[yi][ot][jj] * d + nv[jj] * ba + bi;
        hv[jj] = lrelu(v);
      }
      *(f32x4_t*)(hout + ((size_t)(b * COUT + o) * HO + y) * WO + ox0 + lg * 4) = hv;
    }
  }
}

// ---------------- rgb: coalesced re-read of h ----------------
__global__ __launch_bounds__(256) void k_rgb(
    const float* __restrict__ hout, const float* __restrict__ rgbw, const float* __restrict__ rgbb,
    float* __restrict__ rgbout)
{
  const int bid = blockIdx.x;
  const int b = bid >> 8, y = bid & 255;
  const int xp = threadIdx.x;
  const float* hb = hout + ((size_t)b * COUT * HO * WO) + (size_t)y * WO + xp;
  float r0 = 0.f, r1 = 0.f, r2 = 0.f;
  for (int o = 0; o < COUT; ++o) {
    float v = hb[(size_t)o * HO * WO];
    r0 += rgbw[o] * v;
    r1 += rgbw[COUT + o] * v;
    r2 += rgbw[2 * COUT + o] * v;
  }
  const float her = 0.03f / 8.0f;
  float* rb = rgbout + ((size_t)b * 3 * HO * WO) + (size_t)y * WO + xp;
  rb[0] = r0 * her + rgbb[0];
  rb[(size_t)HO * WO] = r1 * her + rgbb[1];
  rb[2 * (size_t)HO * WO] = r2 * her + rgbb[2];
}

extern "C" void kernel_launch(void* const* d_in, const int* in_sizes, int n_in,
                              void* d_out, int out_size, void* d_ws, size_t ws_size,
                              hipStream_t stream) {
  const float* x      = (const float*)d_in[0];
  const float* w      = (const float*)d_in[1];
  const float* c1w    = (const float*)d_in[2];
  const float* c2w    = (const float*)d_in[3];
  const float* bias1  = (const float*)d_in[4];
  const float* bias2  = (const float*)d_in[5];
  const float* a1w    = (const float*)d_in[6];
  const float* a1b    = (const float*)d_in[7];
  const float* a2w    = (const float*)d_in[8];
  const float* a2b    = (const float*)d_in[9];
  const float* baff1  = (const float*)d_in[10];
  const float* baff2  = (const float*)d_in[11];
  const float* rgbw   = (const float*)d_in[12];
  const float* rgbb   = (const float*)d_in[13];
  const float* noise1 = (const float*)d_in[14];
  const float* noise2 = (const float*)d_in[15];

  const size_t h1_bytes = (size_t)BN * HO * WO * COUT * 2;   // 32 MiB
  unsigned short* h1 = (unsigned short*)d_ws;
  float* s1  = (float*)((char*)d_ws + h1_bytes);
  float* s2  = s1 + BN * CIN;
  float* d1g = s2 + BN * COUT;
  float* d2g = d1g + BN * COUT;
  unsigned short* B1pre = (unsigned short*)((char*)d_ws + h1_bytes + 8192);
  unsigned short* B2pre = B1pre + 144 * 512;

  float* hout   = (float*)d_out;
  float* rgbout = hout + (size_t)BN * COUT * HO * WO;

  k_styles<<<BN, 128, 0, stream>>>(w, c1w, c2w, a1w, a1b, a2w, a2b, s1, s2, d1g, d2g);
  k_wprep<<<216, 256, 0, stream>>>(c1w, c2w, B1pre, B2pre);
  dim3 grid(WO / 16, HO / 16, BN);
  k_conv1<<<grid, 256, 0, stream>>>(x, B1pre, noise1, bias1, baff1, s1, d1g, s2, h1);
  k_conv2<<<grid, 256, 0, stream>>>(h1, B2pre, noise2, bias2, baff2, d2g, hout);
  k_rgb<<<1024, 256, 0, stream>>>(hout, rgbw, rgbb, rgbout);
}

// Round 3
// 181.648 us; speedup vs baseline: 8.5563x; 1.0169x over previous
//
#include <hip/hip_runtime.h>
#include <hip/hip_bf16.h>
#include <math.h>

#define BN 4
#define CIN 128
#define COUT 64
#define WSDIM 512
#define HI 128
#define WI 128
#define HO 256
#define WO 256
#define EPSC 1e-8f
#define GAINC 1.3867504905630728f
#define HE1 (GAINC/33.941125496954285f)
#define HE2 (GAINC/24.0f)
#define SUP (127.0f/255.0f)

typedef __attribute__((ext_vector_type(8))) short s16x8;
typedef __attribute__((ext_vector_type(4))) float f32x4_t;
typedef __attribute__((ext_vector_type(4))) unsigned int u32x4;

static __device__ __forceinline__ float lrelu(float v){ return v > 0.f ? v : 0.2f*v; }
static __device__ __forceinline__ unsigned short bfbits(float v){
  __hip_bfloat16 h = __float2bfloat16(v);
  return *reinterpret_cast<unsigned short*>(&h);
}
static __device__ __forceinline__ unsigned int packbf(float a, float b){
  return (unsigned int)bfbits(a) | ((unsigned int)bfbits(b) << 16);
}

// ---------------- weight prep: B-fragments + wsq ----------------
// B-frag for mfma_f32_16x16x32_bf16: lane l holds k=(l>>4)*8+j, n=l&15.
// Group g=((cc*9+k)*4+ot): c=cc*32+(l>>4)*8+j, o=ot*16+(l&15). Flip+he baked in.
__global__ __launch_bounds__(256) void k_wprep(
    const float* __restrict__ c1w, const float* __restrict__ c2w,
    unsigned short* __restrict__ B1, unsigned short* __restrict__ B2,
    float* __restrict__ wsq1, float* __restrict__ wsq2)
{
  const int g = blockIdx.x, t = threadIdx.x;
  if (g < 144) {
    int cc = g / 36, r = g - cc * 36, k = r >> 2, ot = r & 3;
    for (int e = t; e < 512; e += 256) {
      int l = e >> 3, j = e & 7;
      int c = cc * 32 + (l >> 4) * 8 + j, o = ot * 16 + (l & 15);
      B1[g * 512 + e] = bfbits(c1w[(c * COUT + o) * 9 + (8 - k)] * HE1);
    }
  } else if (g < 288) {
    int g2 = g - 144;
    int cc = g2 / 36, r = g2 - cc * 36, k = r >> 2, ot = r & 3;
    for (int e = t; e < 512; e += 256) {
      int l = e >> 3, j = e & 7;
      int c = cc * 32 + (l >> 4) * 8 + j, o = ot * 16 + (l & 15);
      B2[g2 * 512 + e] = bfbits(c2w[(c * COUT + o) * 9 + (8 - k)] * HE2);
    }
  } else if (g < 292) {       // wsq1: 128x64
    int base = (g - 288) * 2048;
    #pragma unroll
    for (int i = 0; i < 8; ++i) {
      int idx = base + i * 256 + t;
      const float* wp = c1w + (size_t)idx * 9;   // idx = c*64+o
      float s = 0.f;
      #pragma unroll
      for (int k = 0; k < 9; ++k) s += wp[k] * wp[k];
      wsq1[idx] = s;
    }
  } else {                    // wsq2: 64x64 (g=292,293)
    int base = (g - 292) * 2048;
    #pragma unroll
    for (int i = 0; i < 8; ++i) {
      int idx = base + i * 256 + t;
      const float* wp = c2w + (size_t)idx * 9;
      float s = 0.f;
      #pragma unroll
      for (int k = 0; k < 9; ++k) s += wp[k] * wp[k];
      wsq2[idx] = s;
    }
  }
}

// ---------------- styles + demod ----------------
__global__ __launch_bounds__(256) void k_styles(
    const float* __restrict__ w,
    const float* __restrict__ a1w, const float* __restrict__ a1b,
    const float* __restrict__ a2w, const float* __restrict__ a2b,
    const float* __restrict__ wsq1, const float* __restrict__ wsq2,
    float* __restrict__ s1, float* __restrict__ s2,
    float* __restrict__ d1g, float* __restrict__ d2g)
{
  const int b = blockIdx.x, t = threadIdx.x;
  const float he_a = 0.044194173824159216f;
  __shared__ float sh1[CIN];
  __shared__ float sh2[COUT];
  const float* wv = w + b * WSDIM;
  if (t < CIN) {
    float acc = 0.f;
    const float* ap = a1w + t * WSDIM;
    for (int k = 0; k < WSDIM; ++k) acc += ap[k] * wv[k];
    float v = acc * he_a + a1b[t];
    sh1[t] = v; s1[b * CIN + t] = v;
  } else if (t < CIN + COUT) {
    int o = t - CIN;
    float acc = 0.f;
    const float* ap = a2w + o * WSDIM;
    for (int k = 0; k < WSDIM; ++k) acc += ap[k] * wv[k];
    float v = acc * he_a + a2b[o];
    sh2[o] = v; s2[b * COUT + o] = v;
  }
  __syncthreads();
  const int o = t >> 2, p = t & 3;
  float acc = 0.f;
  for (int c = p * 32; c < p * 32 + 32; ++c) acc += sh1[c] * sh1[c] * wsq1[c * COUT + o];
  acc += __shfl_xor(acc, 1); acc += __shfl_xor(acc, 2);
  if (p == 0) d1g[b * COUT + o] = rsqrtf(acc * HE1 * HE1 + EPSC) * GAINC;
  float ac2 = 0.f;
  for (int c = p * 16; c < p * 16 + 16; ++c) ac2 += sh2[c] * sh2[c] * wsq2[c * COUT + o];
  ac2 += __shfl_xor(ac2, 1); ac2 += __shfl_xor(ac2, 2);
  if (p == 0) d2g[b * COUT + o] = rsqrtf(ac2 * HE2 * HE2 + EPSC) * GAINC;
}

// ---------------- k_up: bilinear upsample * s1 -> bf16 channel-last XU ----------------
__global__ __launch_bounds__(256) void k_up(
    const float* __restrict__ x, const float* __restrict__ s1, unsigned short* __restrict__ XU)
{
  const int blk = blockIdx.x;
  const int b = blk >> 8, yo = blk & 255, xo = threadIdx.x;
  float fy = yo * SUP; int y0 = (int)fy; float wy = fy - (float)y0; int y1 = min(y0 + 1, HI - 1);
  float fx = xo * SUP; int x0 = (int)fx; float wx = fx - (float)x0; int x1 = min(x0 + 1, WI - 1);
  const float* s1p = s1 + b * CIN;
  const float* xb = x + (size_t)b * CIN * HI * WI;
  unsigned short* out = XU + (((size_t)b * HO + yo) * WO + xo) * CIN;
  const int p00 = y0 * WI + x0, p01 = y0 * WI + x1, p10 = y1 * WI + x0, p11 = y1 * WI + x1;
  #pragma unroll 4
  for (int c8 = 0; c8 < 16; ++c8) {
    unsigned int pk[4];
    #pragma unroll
    for (int e2 = 0; e2 < 4; ++e2) {
      float vv[2];
      #pragma unroll
      for (int u = 0; u < 2; ++u) {
        int c = c8 * 8 + e2 * 2 + u;
        const float* xc = xb + ((size_t)c << 14);
        float a = xc[p00], bq = xc[p01], cq = xc[p10], dq = xc[p11];
        float t0 = a + (cq - a) * wy;
        float t1 = bq + (dq - bq) * wy;
        vv[u] = (t0 + (t1 - t0) * wx) * s1p[c];
      }
      pk[e2] = packbf(vv[0], vv[1]);
    }
    *(u32x4*)(out + c8 * 8) = *(u32x4*)pk;
  }
}

// ---------------- conv1: implicit GEMM from XU, reg-staged double buffer ----------------
__global__ __launch_bounds__(256) void k_conv1(
    const unsigned short* __restrict__ XU, const unsigned short* __restrict__ B1pre,
    const float* __restrict__ noise1, const float* __restrict__ bias1, const float* __restrict__ baff1,
    const float* __restrict__ d1g, const float* __restrict__ s2,
    unsigned short* __restrict__ h1)
{
  const int b = blockIdx.z;
  const int oy0 = blockIdx.y * 16, ox0 = blockIdx.x * 16;
  const int tid = threadIdx.x;
  const int lane = tid & 63, wv = tid >> 6;
  const int lx = lane & 15, lg = lane >> 4;

  __shared__ unsigned int ldsA[324 * 20];

  f32x4_t acc[4][4];
  #pragma unroll
  for (int i = 0; i < 4; ++i)
    #pragma unroll
    for (int j = 0; j < 4; ++j) acc[i][j] = (f32x4_t){0.f, 0.f, 0.f, 0.f};

  const s16x8* Bb = (const s16x8*)B1pre;

  u32x4 rg[6], rg2[6];
  auto LOAD = [&](int cc, u32x4 (&r)[6]) {
    #pragma unroll
    for (int i = 0; i < 6; ++i) {
      int e = i * 256 + tid;
      u32x4 v = {0, 0, 0, 0};
      if (e < 1296) {
        int pos = e >> 2, q = e & 3;
        int ys = pos / 18, xs = pos - ys * 18;
        int yy = oy0 - 1 + ys, xx = ox0 - 1 + xs;
        if (yy >= 0 && yy < HO && xx >= 0 && xx < WO)
          v = *(const u32x4*)(XU + ((((size_t)b * HO + yy) * WO + xx) * CIN + cc * 32 + q * 8));
      }
      r[i] = v;
    }
  };
  auto STORE = [&](u32x4 (&r)[6]) {
    #pragma unroll
    for (int i = 0; i < 6; ++i) {
      int e = i * 256 + tid;
      if (e < 1296) {
        int pos = e >> 2, q = e & 3;
        *(u32x4*)(ldsA + pos * 20 + q * 4) = r[i];
      }
    }
  };

  LOAD(0, rg);
  for (int cc = 0; cc < 4; ++cc) {
    if (cc) __syncthreads();
    STORE(rg);
    if (cc < 3) LOAD(cc + 1, rg2);
    __syncthreads();
    #pragma unroll
    for (int k = 0; k < 9; ++k) {
      const int dy = k / 3, dx = k - 3 * (k / 3);
      s16x8 b0 = Bb[((cc * 9 + k) * 4 + 0) * 64 + lane];
      s16x8 b1 = Bb[((cc * 9 + k) * 4 + 1) * 64 + lane];
      s16x8 b2 = Bb[((cc * 9 + k) * 4 + 2) * 64 + lane];
      s16x8 b3 = Bb[((cc * 9 + k) * 4 + 3) * 64 + lane];
      #pragma unroll
      for (int yi = 0; yi < 4; ++yi) {
        int row = (wv * 4 + yi + dy) * 18 + (lx + dx);
        s16x8 a = *(const s16x8*)((const char*)ldsA + (size_t)row * 80 + lg * 16);
        acc[yi][0] = __builtin_amdgcn_mfma_f32_16x16x32_bf16(a, b0, acc[yi][0], 0, 0, 0);
        acc[yi][1] = __builtin_amdgcn_mfma_f32_16x16x32_bf16(a, b1, acc[yi][1], 0, 0, 0);
        acc[yi][2] = __builtin_amdgcn_mfma_f32_16x16x32_bf16(a, b2, acc[yi][2], 0, 0, 0);
        acc[yi][3] = __builtin_amdgcn_mfma_f32_16x16x32_bf16(a, b3, acc[yi][3], 0, 0, 0);
      }
    }
    if (cc < 3) {
      #pragma unroll
      for (int i = 0; i < 6; ++i) rg[i] = rg2[i];
    }
  }
  // epilogue: demod + noise + bias + lrelu, fold s2, bf16 channel-last h1
  #pragma unroll
  for (int yi = 0; yi < 4; ++yi) {
    int y = oy0 + wv * 4 + yi;
    f32x4_t nv = *(const f32x4_t*)(noise1 + (size_t)b * HO * WO + (size_t)y * WO + ox0 + lg * 4);
    #pragma unroll
    for (int ot = 0; ot < 4; ++ot) {
      int o = ot * 16 + lx;
      float d = d1g[b * COUT + o], ba = baff1[o], bi = bias1[o], sv = s2[b * COUT + o];
      #pragma unroll
      for (int jj = 0; jj < 4; ++jj) {
        float v = acc[yi][ot][jj] * d + nv[jj] * ba + bi;
        v = lrelu(v) * sv;
        int xg = ox0 + lg * 4 + jj;
        h1[(((size_t)b * HO + y) * WO + xg) * COUT + o] = bfbits(v);
      }
    }
  }
}

// ---------------- conv2: implicit GEMM + fused rgb ----------------
__global__ __launch_bounds__(256) void k_conv2(
    const unsigned short* __restrict__ h1, const unsigned short* __restrict__ B2pre,
    const float* __restrict__ noise2, const float* __restrict__ bias2, const float* __restrict__ baff2,
    const float* __restrict__ d2g, const float* __restrict__ rgbw, const float* __restrict__ rgbb,
    float* __restrict__ hout, float* __restrict__ rgbout)
{
  const int b = blockIdx.z;
  const int oy0 = blockIdx.y * 16, ox0 = blockIdx.x * 16;
  const int tid = threadIdx.x;
  const int lane = tid & 63, wv = tid >> 6;
  const int lx = lane & 15, lg = lane >> 4;

  __shared__ unsigned int ldsA[324 * 20];

  f32x4_t acc[4][4];
  #pragma unroll
  for (int i = 0; i < 4; ++i)
    #pragma unroll
    for (int j = 0; j < 4; ++j) acc[i][j] = (f32x4_t){0.f, 0.f, 0.f, 0.f};

  const s16x8* Bb = (const s16x8*)B2pre;

  u32x4 rg[6], rg2[6];
  auto LOAD = [&](int cc, u32x4 (&r)[6]) {
    #pragma unroll
    for (int i = 0; i < 6; ++i) {
      int e = i * 256 + tid;
      u32x4 v = {0, 0, 0, 0};
      if (e < 1296) {
        int pos = e >> 2, q = e & 3;
        int ys = pos / 18, xs = pos - ys * 18;
        int yy = oy0 - 1 + ys, xx = ox0 - 1 + xs;
        if (yy >= 0 && yy < HO && xx >= 0 && xx < WO)
          v = *(const u32x4*)(h1 + ((((size_t)b * HO + yy) * WO + xx) * COUT + cc * 32 + q * 8));
      }
      r[i] = v;
    }
  };
  auto STORE = [&](u32x4 (&r)[6]) {
    #pragma unroll
    for (int i = 0; i < 6; ++i) {
      int e = i * 256 + tid;
      if (e < 1296) {
        int pos = e >> 2, q = e & 3;
        *(u32x4*)(ldsA + pos * 20 + q * 4) = r[i];
      }
    }
  };

  LOAD(0, rg);
  for (int cc = 0; cc < 2; ++cc) {
    if (cc) __syncthreads();
    STORE(rg);
    if (cc < 1) LOAD(cc + 1, rg2);
    __syncthreads();
    #pragma unroll
    for (int k = 0; k < 9; ++k) {
      const int dy = k / 3, dx = k - 3 * (k / 3);
      s16x8 b0 = Bb[((cc * 9 + k) * 4 + 0) * 64 + lane];
      s16x8 b1 = Bb[((cc * 9 + k) * 4 + 1) * 64 + lane];
      s16x8 b2 = Bb[((cc * 9 + k) * 4 + 2) * 64 + lane];
      s16x8 b3 = Bb[((cc * 9 + k) * 4 + 3) * 64 + lane];
      #pragma unroll
      for (int yi = 0; yi < 4; ++yi) {
        int row = (wv * 4 + yi + dy) * 18 + (lx + dx);
        s16x8 a = *(const s16x8*)((const char*)ldsA + (size_t)row * 80 + lg * 16);
        acc[yi][0] = __builtin_amdgcn_mfma_f32_16x16x32_bf16(a, b0, acc[yi][0], 0, 0, 0);
        acc[yi][1] = __builtin_amdgcn_mfma_f32_16x16x32_bf16(a, b1, acc[yi][1], 0, 0, 0);
        acc[yi][2] = __builtin_amdgcn_mfma_f32_16x16x32_bf16(a, b2, acc[yi][2], 0, 0, 0);
        acc[yi][3] = __builtin_amdgcn_mfma_f32_16x16x32_bf16(a, b3, acc[yi][3], 0, 0, 0);
      }
    }
    if (cc < 1) {
      #pragma unroll
      for (int i = 0; i < 6; ++i) rg[i] = rg2[i];
    }
  }
  const float her = 0.03f / 8.0f;
  #pragma unroll
  for (int yi = 0; yi < 4; ++yi) {
    int y = oy0 + wv * 4 + yi;
    f32x4_t nv = *(const f32x4_t*)(noise2 + (size_t)b * HO * WO + (size_t)y * WO + ox0 + lg * 4);
    float r[3][4];
    #pragma unroll
    for (int ch = 0; ch < 3; ++ch)
      #pragma unroll
      for (int jj = 0; jj < 4; ++jj) r[ch][jj] = 0.f;
    #pragma unroll
    for (int ot = 0; ot < 4; ++ot) {
      int o = ot * 16 + lx;
      float d = d2g[b * COUT + o], ba = baff2[o], bi = bias2[o];
      float w0 = rgbw[o], w1 = rgbw[COUT + o], w2 = rgbw[2 * COUT + o];
      f32x4_t hv;
      #pragma unroll
      for (int jj = 0; jj < 4; ++jj) {
        float v = acc[yi][ot][jj] * d + nv[jj] * ba + bi;
        v = lrelu(v);
        hv[jj] = v;
        r[0][jj] += w0 * v; r[1][jj] += w1 * v; r[2][jj] += w2 * v;
      }
      *(f32x4_t*)(hout + ((size_t)(b * COUT + o) * HO + y) * WO + ox0 + lg * 4) = hv;
    }
    // reduce rgb over the 16 lanes (lx) of this lg-group
    #pragma unroll
    for (int ch = 0; ch < 3; ++ch)
      #pragma unroll
      for (int jj = 0; jj < 4; ++jj) {
        float s = r[ch][jj];
        s += __shfl_xor(s, 1); s += __shfl_xor(s, 2);
        s += __shfl_xor(s, 4); s += __shfl_xor(s, 8);
        r[ch][jj] = s;
      }
    if (lx < 12) {
      float val = 0.f;
      #pragma unroll
      for (int ii = 0; ii < 12; ++ii) if (lx == ii) val = r[ii >> 2][ii & 3];
      int ch = lx >> 2, jj = lx & 3;
      rgbout[(((size_t)(b * 3 + ch)) * HO + y) * WO + ox0 + lg * 4 + jj] = val * her + rgbb[ch];
    }
  }
}

extern "C" void kernel_launch(void* const* d_in, const int* in_sizes, int n_in,
                              void* d_out, int out_size, void* d_ws, size_t ws_size,
                              hipStream_t stream) {
  const float* x      = (const float*)d_in[0];
  const float* w      = (const float*)d_in[1];
  const float* c1w    = (const float*)d_in[2];
  const float* c2w    = (const float*)d_in[3];
  const float* bias1  = (const float*)d_in[4];
  const float* bias2  = (const float*)d_in[5];
  const float* a1w    = (const float*)d_in[6];
  const float* a1b    = (const float*)d_in[7];
  const float* a2w    = (const float*)d_in[8];
  const float* a2b    = (const float*)d_in[9];
  const float* baff1  = (const float*)d_in[10];
  const float* baff2  = (const float*)d_in[11];
  const float* rgbw   = (const float*)d_in[12];
  const float* rgbb   = (const float*)d_in[13];
  const float* noise1 = (const float*)d_in[14];
  const float* noise2 = (const float*)d_in[15];

  // workspace layout
  const size_t h1_bytes = (size_t)BN * HO * WO * COUT * 2;   // 32 MiB
  unsigned short* h1 = (unsigned short*)d_ws;
  char* p = (char*)d_ws + h1_bytes;
  float* s1  = (float*)p;               p += BN * CIN * 4;
  float* s2  = (float*)p;               p += BN * COUT * 4;
  float* d1g = (float*)p;               p += BN * COUT * 4;
  float* d2g = (float*)p;               p += BN * COUT * 4;
  float* wsq1 = (float*)p;              p += CIN * COUT * 4;
  float* wsq2 = (float*)p;              p += COUT * COUT * 4;
  unsigned short* B1pre = (unsigned short*)p;  p += 144 * 512 * 2;
  unsigned short* B2pre = (unsigned short*)p;

  // XU (bf16 channel-last, 67 MB) lives in d_out; fully dead before conv2 writes d_out.
  unsigned short* XU = (unsigned short*)d_out;
  float* hout   = (float*)d_out;
  float* rgbout = hout + (size_t)BN * COUT * HO * WO;

  k_wprep<<<294, 256, 0, stream>>>(c1w, c2w, B1pre, B2pre, wsq1, wsq2);
  k_styles<<<BN, 256, 0, stream>>>(w, a1w, a1b, a2w, a2b, wsq1, wsq2, s1, s2, d1g, d2g);
  k_up<<<BN * HO, 256, 0, stream>>>(x, s1, XU);
  dim3 grid(WO / 16, HO / 16, BN);
  k_conv1<<<grid, 256, 0, stream>>>(XU, B1pre, noise1, bias1, baff1, d1g, s2, h1);
  k_conv2<<<grid, 256, 0, stream>>>(h1, B2pre, noise2, bias2, baff2, d2g, rgbw, rgbb, hout, rgbout);
}

// Round 4
// 140.780 us; speedup vs baseline: 11.0402x; 1.2903x over previous
//
#include <hip/hip_runtime.h>
#include <hip/hip_bf16.h>
#include <math.h>

#define BN 4
#define CIN 128
#define COUT 64
#define WSDIM 512
#define HI 128
#define WI 128
#define HO 256
#define WO 256
#define EPSC 1e-8f
#define GAINC 1.3867504905630728f
#define HE1 (GAINC/33.941125496954285f)
#define HE2 (GAINC/24.0f)
#define SUP (127.0f/255.0f)

typedef __attribute__((ext_vector_type(8))) short s16x8;
typedef __attribute__((ext_vector_type(4))) float f32x4_t;
typedef __attribute__((ext_vector_type(4))) unsigned int u32x4;

static __device__ __forceinline__ float lrelu(float v){ return v > 0.f ? v : 0.2f*v; }
static __device__ __forceinline__ unsigned short bfbits(float v){
  __hip_bfloat16 h = __float2bfloat16(v);
  return *reinterpret_cast<unsigned short*>(&h);
}
static __device__ __forceinline__ unsigned int packbf(float a, float b){
  return (unsigned int)bfbits(a) | ((unsigned int)bfbits(b) << 16);
}

// ---------------- weight prep: B-fragments + wsq ----------------
__global__ __launch_bounds__(256) void k_wprep(
    const float* __restrict__ c1w, const float* __restrict__ c2w,
    unsigned short* __restrict__ B1, unsigned short* __restrict__ B2,
    float* __restrict__ wsq1, float* __restrict__ wsq2)
{
  const int g = blockIdx.x, t = threadIdx.x;
  if (g < 144) {
    int cc = g / 36, r = g - cc * 36, k = r >> 2, ot = r & 3;
    for (int e = t; e < 512; e += 256) {
      int l = e >> 3, j = e & 7;
      int c = cc * 32 + (l >> 4) * 8 + j, o = ot * 16 + (l & 15);
      B1[g * 512 + e] = bfbits(c1w[(c * COUT + o) * 9 + (8 - k)] * HE1);
    }
  } else if (g < 288) {
    int g2 = g - 144;
    int cc = g2 / 36, r = g2 - cc * 36, k = r >> 2, ot = r & 3;
    for (int e = t; e < 512; e += 256) {
      int l = e >> 3, j = e & 7;
      int c = cc * 32 + (l >> 4) * 8 + j, o = ot * 16 + (l & 15);
      B2[g2 * 512 + e] = bfbits(c2w[(c * COUT + o) * 9 + (8 - k)] * HE2);
    }
  } else if (g < 292) {
    int base = (g - 288) * 2048;
    #pragma unroll
    for (int i = 0; i < 8; ++i) {
      int idx = base + i * 256 + t;
      const float* wp = c1w + (size_t)idx * 9;
      float s = 0.f;
      #pragma unroll
      for (int k = 0; k < 9; ++k) s += wp[k] * wp[k];
      wsq1[idx] = s;
    }
  } else {
    int base = (g - 292) * 2048;
    #pragma unroll
    for (int i = 0; i < 8; ++i) {
      int idx = base + i * 256 + t;
      const float* wp = c2w + (size_t)idx * 9;
      float s = 0.f;
      #pragma unroll
      for (int k = 0; k < 9; ++k) s += wp[k] * wp[k];
      wsq2[idx] = s;
    }
  }
}

// ---------------- styles + demod ----------------
__global__ __launch_bounds__(256) void k_styles(
    const float* __restrict__ w,
    const float* __restrict__ a1w, const float* __restrict__ a1b,
    const float* __restrict__ a2w, const float* __restrict__ a2b,
    const float* __restrict__ wsq1, const float* __restrict__ wsq2,
    float* __restrict__ s1, float* __restrict__ s2,
    float* __restrict__ d1g, float* __restrict__ d2g)
{
  const int b = blockIdx.x, t = threadIdx.x;
  const float he_a = 0.044194173824159216f;
  __shared__ float sh1[CIN];
  __shared__ float sh2[COUT];
  const float* wv = w + b * WSDIM;
  if (t < CIN) {
    float acc = 0.f;
    const float* ap = a1w + t * WSDIM;
    for (int k = 0; k < WSDIM; ++k) acc += ap[k] * wv[k];
    float v = acc * he_a + a1b[t];
    sh1[t] = v; s1[b * CIN + t] = v;
  } else if (t < CIN + COUT) {
    int o = t - CIN;
    float acc = 0.f;
    const float* ap = a2w + o * WSDIM;
    for (int k = 0; k < WSDIM; ++k) acc += ap[k] * wv[k];
    float v = acc * he_a + a2b[o];
    sh2[o] = v; s2[b * COUT + o] = v;
  }
  __syncthreads();
  const int o = t >> 2, p = t & 3;
  float acc = 0.f;
  for (int c = p * 32; c < p * 32 + 32; ++c) acc += sh1[c] * sh1[c] * wsq1[c * COUT + o];
  acc += __shfl_xor(acc, 1); acc += __shfl_xor(acc, 2);
  if (p == 0) d1g[b * COUT + o] = rsqrtf(acc * HE1 * HE1 + EPSC) * GAINC;
  float ac2 = 0.f;
  for (int c = p * 16; c < p * 16 + 16; ++c) ac2 += sh2[c] * sh2[c] * wsq2[c * COUT + o];
  ac2 += __shfl_xor(ac2, 1); ac2 += __shfl_xor(ac2, 2);
  if (p == 0) d2g[b * COUT + o] = rsqrtf(ac2 * HE2 * HE2 + EPSC) * GAINC;
}

// ---------------- k_up: LDS-staged transpose; coalesced both sides ----------------
// One block per (b, yo). LDS xs[r][x][c]: r=y0/y1 row, x=0..127, c=32-ch chunk (stride 36).
__global__ __launch_bounds__(256) void k_up(
    const float* __restrict__ x, const float* __restrict__ s1, unsigned short* __restrict__ XU)
{
  const int bid = blockIdx.x;
  const int swz = (bid & 7) * 128 + (bid >> 3);   // XCD gets 128 contiguous rows
  const int b = swz >> 8, yo = swz & 255;
  const int tid = threadIdx.x;
  __shared__ float xs[2][128][36];

  const float fy = yo * SUP;
  const int y0 = (int)fy;
  const float wy = fy - (float)y0;
  const int y1 = min(y0 + 1, HI - 1);

  const float* xb = x + ((size_t)b * CIN << 14);
  unsigned short* outb = XU + (((size_t)b * HO + yo) * WO) * (size_t)CIN;
  const int ch0 = (tid & 3) * 8;

  for (int chunk = 0; chunk < 4; ++chunk) {
    if (chunk) __syncthreads();
    // ---- load: 32 ch x {y0,y1} rows of 128 floats, coalesced 16B runs ----
    #pragma unroll
    for (int i = 0; i < 2; ++i) {
      int rid = i * 32 + (tid >> 3);          // 0..63
      int c = rid >> 1, r = rid & 1;
      const float* src = xb + (((size_t)(chunk * 32 + c)) << 14) + (r ? y1 : y0) * WI + (tid & 7) * 4;
      #pragma unroll
      for (int k = 0; k < 4; ++k) {
        f32x4_t v = *(const f32x4_t*)(src + k * 32);
        int xp = (tid & 7) * 4 + k * 32;
        xs[r][xp + 0][c] = v[0];
        xs[r][xp + 1][c] = v[1];
        xs[r][xp + 2][c] = v[2];
        xs[r][xp + 3][c] = v[3];
      }
    }
    f32x4_t sA = *(const f32x4_t*)(s1 + b * CIN + chunk * 32 + ch0);
    f32x4_t sB = *(const f32x4_t*)(s1 + b * CIN + chunk * 32 + ch0 + 4);
    __syncthreads();
    // ---- compute + write: lane owns (pixel, 8 ch); wave writes 16 full 64B lines ----
    #pragma unroll
    for (int pp = 0; pp < 4; ++pp) {
      int pix = pp * 64 + (tid >> 2);
      float fx = pix * SUP;
      int x0 = (int)fx;
      float wx = fx - (float)x0;
      int x1 = min(x0 + 1, WI - 1);

      f32x4_t a0A = *(const f32x4_t*)&xs[0][x0][ch0];
      f32x4_t a1A = *(const f32x4_t*)&xs[0][x1][ch0];
      f32x4_t c0A = *(const f32x4_t*)&xs[1][x0][ch0];
      f32x4_t c1A = *(const f32x4_t*)&xs[1][x1][ch0];
      f32x4_t a0B = *(const f32x4_t*)&xs[0][x0][ch0 + 4];
      f32x4_t a1B = *(const f32x4_t*)&xs[0][x1][ch0 + 4];
      f32x4_t c0B = *(const f32x4_t*)&xs[1][x0][ch0 + 4];
      f32x4_t c1B = *(const f32x4_t*)&xs[1][x1][ch0 + 4];

      float vv[8];
      #pragma unroll
      for (int e = 0; e < 4; ++e) {
        float t0 = a0A[e] + (c0A[e] - a0A[e]) * wy;
        float t1 = a1A[e] + (c1A[e] - a1A[e]) * wy;
        vv[e] = (t0 + (t1 - t0) * wx) * sA[e];
      }
      #pragma unroll
      for (int e = 0; e < 4; ++e) {
        float t0 = a0B[e] + (c0B[e] - a0B[e]) * wy;
        float t1 = a1B[e] + (c1B[e] - a1B[e]) * wy;
        vv[4 + e] = (t0 + (t1 - t0) * wx) * sB[e];
      }
      unsigned int pk[4];
      pk[0] = packbf(vv[0], vv[1]); pk[1] = packbf(vv[2], vv[3]);
      pk[2] = packbf(vv[4], vv[5]); pk[3] = packbf(vv[6], vv[7]);
      *(u32x4*)(outb + (size_t)pix * CIN + chunk * 32 + ch0) = *(u32x4*)pk;
    }
  }
}

// ---------------- conv1: implicit GEMM from XU, reg-staged double buffer ----------------
__global__ __launch_bounds__(256) void k_conv1(
    const unsigned short* __restrict__ XU, const unsigned short* __restrict__ B1pre,
    const float* __restrict__ noise1, const float* __restrict__ bias1, const float* __restrict__ baff1,
    const float* __restrict__ d1g, const float* __restrict__ s2,
    unsigned short* __restrict__ h1)
{
  const int b = blockIdx.z;
  const int oy0 = blockIdx.y * 16, ox0 = blockIdx.x * 16;
  const int tid = threadIdx.x;
  const int lane = tid & 63, wv = tid >> 6;
  const int lx = lane & 15, lg = lane >> 4;

  __shared__ unsigned int ldsA[324 * 20];

  f32x4_t acc[4][4];
  #pragma unroll
  for (int i = 0; i < 4; ++i)
    #pragma unroll
    for (int j = 0; j < 4; ++j) acc[i][j] = (f32x4_t){0.f, 0.f, 0.f, 0.f};

  const s16x8* Bb = (const s16x8*)B1pre;

  u32x4 rg[6], rg2[6];
  auto LOAD = [&](int cc, u32x4 (&r)[6]) {
    #pragma unroll
    for (int i = 0; i < 6; ++i) {
      int e = i * 256 + tid;
      u32x4 v = {0, 0, 0, 0};
      if (e < 1296) {
        int pos = e >> 2, q = e & 3;
        int ys = pos / 18, xs = pos - ys * 18;
        int yy = oy0 - 1 + ys, xx = ox0 - 1 + xs;
        if (yy >= 0 && yy < HO && xx >= 0 && xx < WO)
          v = *(const u32x4*)(XU + ((((size_t)b * HO + yy) * WO + xx) * CIN + cc * 32 + q * 8));
      }
      r[i] = v;
    }
  };
  auto STORE = [&](u32x4 (&r)[6]) {
    #pragma unroll
    for (int i = 0; i < 6; ++i) {
      int e = i * 256 + tid;
      if (e < 1296) {
        int pos = e >> 2, q = e & 3;
        *(u32x4*)(ldsA + pos * 20 + q * 4) = r[i];
      }
    }
  };

  LOAD(0, rg);
  for (int cc = 0; cc < 4; ++cc) {
    if (cc) __syncthreads();
    STORE(rg);
    if (cc < 3) LOAD(cc + 1, rg2);
    __syncthreads();
    #pragma unroll
    for (int k = 0; k < 9; ++k) {
      const int dy = k / 3, dx = k - 3 * (k / 3);
      s16x8 b0 = Bb[((cc * 9 + k) * 4 + 0) * 64 + lane];
      s16x8 b1 = Bb[((cc * 9 + k) * 4 + 1) * 64 + lane];
      s16x8 b2 = Bb[((cc * 9 + k) * 4 + 2) * 64 + lane];
      s16x8 b3 = Bb[((cc * 9 + k) * 4 + 3) * 64 + lane];
      #pragma unroll
      for (int yi = 0; yi < 4; ++yi) {
        int row = (wv * 4 + yi + dy) * 18 + (lx + dx);
        s16x8 a = *(const s16x8*)((const char*)ldsA + (size_t)row * 80 + lg * 16);
        acc[yi][0] = __builtin_amdgcn_mfma_f32_16x16x32_bf16(a, b0, acc[yi][0], 0, 0, 0);
        acc[yi][1] = __builtin_amdgcn_mfma_f32_16x16x32_bf16(a, b1, acc[yi][1], 0, 0, 0);
        acc[yi][2] = __builtin_amdgcn_mfma_f32_16x16x32_bf16(a, b2, acc[yi][2], 0, 0, 0);
        acc[yi][3] = __builtin_amdgcn_mfma_f32_16x16x32_bf16(a, b3, acc[yi][3], 0, 0, 0);
      }
    }
    if (cc < 3) {
      #pragma unroll
      for (int i = 0; i < 6; ++i) rg[i] = rg2[i];
    }
  }
  #pragma unroll
  for (int yi = 0; yi < 4; ++yi) {
    int y = oy0 + wv * 4 + yi;
    f32x4_t nv = *(const f32x4_t*)(noise1 + (size_t)b * HO * WO + (size_t)y * WO + ox0 + lg * 4);
    #pragma unroll
    for (int ot = 0; ot < 4; ++ot) {
      int o = ot * 16 + lx;
      float d = d1g[b * COUT + o], ba = baff1[o], bi = bias1[o], sv = s2[b * COUT + o];
      #pragma unroll
      for (int jj = 0; jj < 4; ++jj) {
        float v = acc[yi][ot][jj] * d + nv[jj] * ba + bi;
        v = lrelu(v) * sv;
        int xg = ox0 + lg * 4 + jj;
        h1[(((size_t)b * HO + y) * WO + xg) * COUT + o] = bfbits(v);
      }
    }
  }
}

// ---------------- conv2: implicit GEMM + fused rgb ----------------
__global__ __launch_bounds__(256) void k_conv2(
    const unsigned short* __restrict__ h1, const unsigned short* __restrict__ B2pre,
    const float* __restrict__ noise2, const float* __restrict__ bias2, const float* __restrict__ baff2,
    const float* __restrict__ d2g, const float* __restrict__ rgbw, const float* __restrict__ rgbb,
    float* __restrict__ hout, float* __restrict__ rgbout)
{
  const int b = blockIdx.z;
  const int oy0 = blockIdx.y * 16, ox0 = blockIdx.x * 16;
  const int tid = threadIdx.x;
  const int lane = tid & 63, wv = tid >> 6;
  const int lx = lane & 15, lg = lane >> 4;

  __shared__ unsigned int ldsA[324 * 20];

  f32x4_t acc[4][4];
  #pragma unroll
  for (int i = 0; i < 4; ++i)
    #pragma unroll
    for (int j = 0; j < 4; ++j) acc[i][j] = (f32x4_t){0.f, 0.f, 0.f, 0.f};

  const s16x8* Bb = (const s16x8*)B2pre;

  u32x4 rg[6], rg2[6];
  auto LOAD = [&](int cc, u32x4 (&r)[6]) {
    #pragma unroll
    for (int i = 0; i < 6; ++i) {
      int e = i * 256 + tid;
      u32x4 v = {0, 0, 0, 0};
      if (e < 1296) {
        int pos = e >> 2, q = e & 3;
        int ys = pos / 18, xs = pos - ys * 18;
        int yy = oy0 - 1 + ys, xx = ox0 - 1 + xs;
        if (yy >= 0 && yy < HO && xx >= 0 && xx < WO)
          v = *(const u32x4*)(h1 + ((((size_t)b * HO + yy) * WO + xx) * COUT + cc * 32 + q * 8));
      }
      r[i] = v;
    }
  };
  auto STORE = [&](u32x4 (&r)[6]) {
    #pragma unroll
    for (int i = 0; i < 6; ++i) {
      int e = i * 256 + tid;
      if (e < 1296) {
        int pos = e >> 2, q = e & 3;
        *(u32x4*)(ldsA + pos * 20 + q * 4) = r[i];
      }
    }
  };

  LOAD(0, rg);
  for (int cc = 0; cc < 2; ++cc) {
    if (cc) __syncthreads();
    STORE(rg);
    if (cc < 1) LOAD(cc + 1, rg2);
    __syncthreads();
    #pragma unroll
    for (int k = 0; k < 9; ++k) {
      const int dy = k / 3, dx = k - 3 * (k / 3);
      s16x8 b0 = Bb[((cc * 9 + k) * 4 + 0) * 64 + lane];
      s16x8 b1 = Bb[((cc * 9 + k) * 4 + 1) * 64 + lane];
      s16x8 b2 = Bb[((cc * 9 + k) * 4 + 2) * 64 + lane];
      s16x8 b3 = Bb[((cc * 9 + k) * 4 + 3) * 64 + lane];
      #pragma unroll
      for (int yi = 0; yi < 4; ++yi) {
        int row = (wv * 4 + yi + dy) * 18 + (lx + dx);
        s16x8 a = *(const s16x8*)((const char*)ldsA + (size_t)row * 80 + lg * 16);
        acc[yi][0] = __builtin_amdgcn_mfma_f32_16x16x32_bf16(a, b0, acc[yi][0], 0, 0, 0);
        acc[yi][1] = __builtin_amdgcn_mfma_f32_16x16x32_bf16(a, b1, acc[yi][1], 0, 0, 0);
        acc[yi][2] = __builtin_amdgcn_mfma_f32_16x16x32_bf16(a, b2, acc[yi][2], 0, 0, 0);
        acc[yi][3] = __builtin_amdgcn_mfma_f32_16x16x32_bf16(a, b3, acc[yi][3], 0, 0, 0);
      }
    }
    if (cc < 1) {
      #pragma unroll
      for (int i = 0; i < 6; ++i) rg[i] = rg2[i];
    }
  }
  const float her = 0.03f / 8.0f;
  #pragma unroll
  for (int yi = 0; yi < 4; ++yi) {
    int y = oy0 + wv * 4 + yi;
    f32x4_t nv = *(const f32x4_t*)(noise2 + (size_t)b * HO * WO + (size_t)y * WO + ox0 + lg * 4);
    float r[3][4];
    #pragma unroll
    for (int ch = 0; ch < 3; ++ch)
      #pragma unroll
      for (int jj = 0; jj < 4; ++jj) r[ch][jj] = 0.f;
    #pragma unroll
    for (int ot = 0; ot < 4; ++ot) {
      int o = ot * 16 + lx;
      float d = d2g[b * COUT + o], ba = baff2[o], bi = bias2[o];
      float w0 = rgbw[o], w1 = rgbw[COUT + o], w2 = rgbw[2 * COUT + o];
      f32x4_t hv;
      #pragma unroll
      for (int jj = 0; jj < 4; ++jj) {
        float v = acc[yi][ot][jj] * d + nv[jj] * ba + bi;
        v = lrelu(v);
        hv[jj] = v;
        r[0][jj] += w0 * v; r[1][jj] += w1 * v; r[2][jj] += w2 * v;
      }
      *(f32x4_t*)(hout + ((size_t)(b * COUT + o) * HO + y) * WO + ox0 + lg * 4) = hv;
    }
    #pragma unroll
    for (int ch = 0; ch < 3; ++ch)
      #pragma unroll
      for (int jj = 0; jj < 4; ++jj) {
        float s = r[ch][jj];
        s += __shfl_xor(s, 1); s += __shfl_xor(s, 2);
        s += __shfl_xor(s, 4); s += __shfl_xor(s, 8);
        r[ch][jj] = s;
      }
    if (lx < 12) {
      float val = 0.f;
      #pragma unroll
      for (int ii = 0; ii < 12; ++ii) if (lx == ii) val = r[ii >> 2][ii & 3];
      int ch = lx >> 2, jj = lx & 3;
      rgbout[(((size_t)(b * 3 + ch)) * HO + y) * WO + ox0 + lg * 4 + jj] = val * her + rgbb[ch];
    }
  }
}

extern "C" void kernel_launch(void* const* d_in, const int* in_sizes, int n_in,
                              void* d_out, int out_size, void* d_ws, size_t ws_size,
                              hipStream_t stream) {
  const float* x      = (const float*)d_in[0];
  const float* w      = (const float*)d_in[1];
  const float* c1w    = (const float*)d_in[2];
  const float* c2w    = (const float*)d_in[3];
  const float* bias1  = (const float*)d_in[4];
  const float* bias2  = (const float*)d_in[5];
  const float* a1w    = (const float*)d_in[6];
  const float* a1b    = (const float*)d_in[7];
  const float* a2w    = (const float*)d_in[8];
  const float* a2b    = (const float*)d_in[9];
  const float* baff1  = (const float*)d_in[10];
  const float* baff2  = (const float*)d_in[11];
  const float* rgbw   = (const float*)d_in[12];
  const float* rgbb   = (const float*)d_in[13];
  const float* noise1 = (const float*)d_in[14];
  const float* noise2 = (const float*)d_in[15];

  const size_t h1_bytes = (size_t)BN * HO * WO * COUT * 2;   // 32 MiB
  unsigned short* h1 = (unsigned short*)d_ws;
  char* p = (char*)d_ws + h1_bytes;
  float* s1  = (float*)p;               p += BN * CIN * 4;
  float* s2  = (float*)p;               p += BN * COUT * 4;
  float* d1g = (float*)p;               p += BN * COUT * 4;
  float* d2g = (float*)p;               p += BN * COUT * 4;
  float* wsq1 = (float*)p;              p += CIN * COUT * 4;
  float* wsq2 = (float*)p;              p += COUT * COUT * 4;
  unsigned short* B1pre = (unsigned short*)p;  p += 144 * 512 * 2;
  unsigned short* B2pre = (unsigned short*)p;

  // XU (bf16 channel-last, 64 MiB) lives in d_out; dead before conv2 writes hout.
  unsigned short* XU = (unsigned short*)d_out;
  float* hout   = (float*)d_out;
  float* rgbout = hout + (size_t)BN * COUT * HO * WO;

  k_wprep<<<294, 256, 0, stream>>>(c1w, c2w, B1pre, B2pre, wsq1, wsq2);
  k_styles<<<BN, 256, 0, stream>>>(w, a1w, a1b, a2w, a2b, wsq1, wsq2, s1, s2, d1g, d2g);
  k_up<<<BN * HO, 256, 0, stream>>>(x, s1, XU);
  dim3 grid(WO / 16, HO / 16, BN);
  k_conv1<<<grid, 256, 0, stream>>>(XU, B1pre, noise1, bias1, baff1, d1g, s2, h1);
  k_conv2<<<grid, 256, 0, stream>>>(h1, B2pre, noise2, bias2, baff2, d2g, rgbw, rgbb, hout, rgbout);
}